// Round 3
// baseline (243.244 us; speedup 1.0000x reference)
//
#include <hip/hip_runtime.h>

typedef unsigned short u16;
typedef unsigned int u32;
typedef __attribute__((ext_vector_type(4))) float f32x4;
typedef __attribute__((ext_vector_type(8))) short s16x8;
typedef __attribute__((ext_vector_type(4))) u16 u16x4;
typedef __attribute__((ext_vector_type(2))) u32 u32x2;

#define L2E 1.4426950408889634f
#define QSCALE 0.18033688011112042f /* (1/8) * log2(e) */

__device__ __forceinline__ float bf2f(u16 u) {
    union { u32 i; float f; } v; v.i = ((u32)u) << 16; return v.f;
}
__device__ __forceinline__ u16 f2bf(float f) {  // RNE
    union { float f; u32 i; } v; v.f = f;
    return (u16)((v.i + 0x7fffu + ((v.i >> 16) & 1u)) >> 16);
}
// pack hi16(a) | hi16(b)<<16  (bf16 truncation, 1-2 ops)
__device__ __forceinline__ u32 pack_hi(float a, float b) {
    union { float f; u32 i; } x, y; x.f = a; y.f = b;
    return (x.i >> 16) | (y.i & 0xFFFF0000u);
}
// bf16 stored in lo/hi half of a u32 -> f32 (1 VALU op each)
__device__ __forceinline__ float bflo(u32 w) {
    union { u32 i; float f; } v; v.i = w << 16; return v.f;
}
__device__ __forceinline__ float bfhi(u32 w) {
    union { u32 i; float f; } v; v.i = w & 0xFFFF0000u; return v.f;
}

// async global->LDS, 16B per lane; LDS dest = wave-uniform base + lane*16
__device__ __forceinline__ void gl2lds16(const u16* g, u16* l) {
    __builtin_amdgcn_global_load_lds(
        (const __attribute__((address_space(1))) void*)g,
        (__attribute__((address_space(3))) void*)l, 16, 0, 0);
}

// ---------------------------------------------------------------------------
// prep_kernel = conv (blocks 0..9215) + lg (blocks 9216..13311).
// conv: 6 fp32 tensors (Qin,KVin,Wq,Wk,Wv,Wo) -> bf16 flat region.
// lg:   LGx pre-swizzled gate, flat idx ((((b*128+t16)*32+kt)*64)+lane)*16
//       holds log2(sigmoid(gw*SC+gb)+1e-8) for q=t16*16+(lane&15),
//       k=kt*64+kk*16+(lane>>4)*4+reg.
// ---------------------------------------------------------------------------
__global__ __launch_bounds__(256) void prep_kernel(
    const float* __restrict__ s0, const float* __restrict__ s1,
    const float* __restrict__ s2, const float* __restrict__ s3,
    const float* __restrict__ s4, const float* __restrict__ s5,
    u16* __restrict__ dst,
    const float* __restrict__ SC, const float* __restrict__ gwp,
    const float* __restrict__ gbp, u16* __restrict__ LGx)
{
    if (blockIdx.x < 9216) {
        int e = (blockIdx.x * 256 + threadIdx.x) * 4;
        const float* src; int off;
        if      (e < 4194304) { src = s0; off = e; }
        else if (e < 8388608) { src = s1; off = e - 4194304; }
        else if (e < 8650752) { src = s2; off = e - 8388608; }
        else if (e < 8912896) { src = s3; off = e - 8650752; }
        else if (e < 9175040) { src = s4; off = e - 8912896; }
        else                  { src = s5; off = e - 9175040; }
        f32x4 f = *(const f32x4*)(src + off);
        u16x4 o;
#pragma unroll
        for (int j = 0; j < 4; ++j) o[j] = f2bf(f[j]);
        *(u16x4*)(dst + e) = o;
    } else {
        const int flat = (blockIdx.x - 9216) * 256 + threadIdx.x;
        const int lane = flat & 63;
        const int kt   = (flat >> 6) & 31;
        const int t16  = (flat >> 11) & 127;
        const int b    = flat >> 18;
        const int l16 = lane & 15, quad = lane >> 4;
        const float tA = -gwp[0] * L2E, tB = -gbp[0] * L2E;
        const float* row = SC + ((size_t)b * 2048 + t16 * 16 + l16) * 2048
                              + kt * 64 + quad * 4;
        __align__(16) u16 tmp[16];
#pragma unroll
        for (int kk = 0; kk < 4; ++kk) {
            f32x4 x = *(const f32x4*)(row + kk * 16);
#pragma unroll
            for (int reg = 0; reg < 4; ++reg) {
                float g = __builtin_amdgcn_rcpf(
                    1.0f + __builtin_amdgcn_exp2f(tA * x[reg] + tB)) + 1e-8f;
                tmp[kk * 4 + reg] = f2bf(__builtin_amdgcn_logf(g));  // log2
            }
        }
        u16* d = LGx + (size_t)flat * 16;
        *(uint4*)d       = *(uint4*)tmp;
        *(uint4*)(d + 8) = *(uint4*)(tmp + 8);
    }
}

// ---------------------------------------------------------------------------
// GEMM core, double-buffered: C[128x128] = A[128x512]*B^T, bf16.
// ---------------------------------------------------------------------------
__device__ __forceinline__ void gemm_core(
    const u16* __restrict__ A, const u16* __restrict__ Bw,
    int m0, int n0, u16* As, u16* Bs, f32x4 acc[4][4])
{
    const int tid = threadIdx.x;
    const int lane = tid & 63, w = tid >> 6;
    const int wm = w >> 1, wn = w & 1;
    const int l16 = lane & 15, quad = lane >> 4;
    const int srow = (lane >> 2), sch = (lane & 3) * 8;
    const f32x4 vzero = {0.f, 0.f, 0.f, 0.f};
#pragma unroll
    for (int i = 0; i < 4; ++i)
#pragma unroll
        for (int j = 0; j < 4; ++j) acc[i][j] = vzero;

    // prologue: stage kt=0 into buffer 0
#pragma unroll
    for (int j = 0; j < 2; ++j) {
        int row = w * 32 + j * 16 + srow;
        gl2lds16(&A[(size_t)(m0 + row) * 512 + sch], &As[w * 1024 + j * 512]);
        gl2lds16(&Bw[(size_t)(n0 + row) * 512 + sch], &Bs[w * 1024 + j * 512]);
    }
    for (int kt = 0; kt < 16; ++kt) {
        __syncthreads();  // buf[kt&1] ready (drains each wave's staging)
        const int cur = (kt & 1) * 4096;
        if (kt < 15) {
            const int nxt = ((kt + 1) & 1) * 4096;
#pragma unroll
            for (int j = 0; j < 2; ++j) {
                int row = w * 32 + j * 16 + srow;
                gl2lds16(&A[(size_t)(m0 + row) * 512 + (kt + 1) * 32 + sch],
                         &As[nxt + w * 1024 + j * 512]);
                gl2lds16(&Bw[(size_t)(n0 + row) * 512 + (kt + 1) * 32 + sch],
                         &Bs[nxt + w * 1024 + j * 512]);
            }
        }
        s16x8 af[4], bfr[4];
#pragma unroll
        for (int mt = 0; mt < 4; ++mt)
            af[mt] = *(const s16x8*)&As[cur + (wm * 64 + mt * 16 + l16) * 32 + quad * 8];
#pragma unroll
        for (int nt = 0; nt < 4; ++nt)
            bfr[nt] = *(const s16x8*)&Bs[cur + (wn * 64 + nt * 16 + l16) * 32 + quad * 8];
#pragma unroll
        for (int mt = 0; mt < 4; ++mt)
#pragma unroll
            for (int nt = 0; nt < 4; ++nt)
                acc[mt][nt] = __builtin_amdgcn_mfma_f32_16x16x32_bf16(
                    af[mt], bfr[nt], acc[mt][nt], 0, 0, 0);
    }
}

// ---------------------------------------------------------------------------
// QKV projection. job 0=Q (scaled, ->[B,H,N,64]), 1=K, 2=V (-> [B,H,64,N]).
// ---------------------------------------------------------------------------
__global__ __launch_bounds__(256) void proj_kernel(
    const u16* __restrict__ cQin, const u16* __restrict__ cKV,
    const u16* __restrict__ cW,
    const float* __restrict__ bq, const float* __restrict__ bk,
    const float* __restrict__ bv,
    u16* __restrict__ Qh, u16* __restrict__ Kh, u16* __restrict__ Vt)
{
    __shared__ __align__(16) u16 As[2 * 4096];
    __shared__ __align__(16) u16 Bs[2 * 4096];
    const int job = blockIdx.z;
    const u16* A = (job == 0) ? cQin : cKV;
    const u16* W = cW + (size_t)job * 262144;
    const float* bias = (job == 0) ? bq : (job == 1 ? bk : bv);
    const int m0 = blockIdx.y * 128, n0 = blockIdx.x * 128;
    f32x4 acc[4][4];
    gemm_core(A, W, m0, n0, As, Bs, acc);

    const int tid = threadIdx.x, lane = tid & 63, w = tid >> 6;
    const int wm = w >> 1, wn = w & 1, l16 = lane & 15, quad = lane >> 4;
#pragma unroll
    for (int nt = 0; nt < 4; ++nt) {
        int j = n0 + wn * 64 + nt * 16 + l16;
        float bj = bias[j];
        int h = j >> 6, d = j & 63;
#pragma unroll
        for (int mt = 0; mt < 4; ++mt) {
            int trow = m0 + wm * 64 + mt * 16 + quad * 4;
            int bb = trow >> 11, nn = trow & 2047;
            int bh = bb * 8 + h;
            if (job == 2) {
                u16x4 pv;
#pragma unroll
                for (int reg = 0; reg < 4; ++reg) pv[reg] = f2bf(acc[mt][nt][reg] + bj);
                *(u16x4*)&Vt[(size_t)(bh * 64 + d) * 2048 + nn] = pv;
            } else if (job == 0) {
#pragma unroll
                for (int reg = 0; reg < 4; ++reg)
                    Qh[(size_t)(bh * 2048 + nn + reg) * 64 + d] =
                        f2bf((acc[mt][nt][reg] + bj) * QSCALE);
            } else {
#pragma unroll
                for (int reg = 0; reg < 4; ++reg)
                    Kh[(size_t)(bh * 2048 + nn + reg) * 64 + d] =
                        f2bf(acc[mt][nt][reg] + bj);
            }
        }
    }
}

// ---------------------------------------------------------------------------
// Attention. Block = 512 thr = 8 waves = (1 head, 128 q-rows); wave = 16 q.
// Grid (16,8,4) = 512 blocks = 2/CU. KVBLK=128: 16 K-tiles, one barrier each
// (half the barrier count of the 64-key version). K/V double-buffered via
// global_load_lds (64 KiB LDS). All ds_read addresses are 4 precomputed base
// registers + compile-time immediates, using
//   (kc*4+quad)^(l16&7) == (quad^(s&3)) + ((kc*4)^(s&4)),  s = l16&7.
// LG folded into QK^T via MFMA C-init; P redistributed to the PV A-fragment
// layout with permlane32_swap+permlane16_swap (no LDS round trip).
// ---------------------------------------------------------------------------
__global__ __launch_bounds__(512, 4) void attn_kernel(
    const u16* __restrict__ Qh, const u16* __restrict__ Kh,
    const u16* __restrict__ Vt, const u16* __restrict__ LGx,
    u16* __restrict__ Ob)
{
    __shared__ __align__(16) u16 Ks[2][8192];      // [buf][key(128)][d(64)] swz
    __shared__ __align__(16) u16 Vs[2][8192];      // [buf][d(64)][key(128)] swz
    const int tid = threadIdx.x;
    const int w = tid >> 6, lane = tid & 63;
    const int l16 = lane & 15, quad = lane >> 4;
    const int b = blockIdx.z, head = blockIdx.y, qg = blockIdx.x;
    const int bh = b * 8 + head;
    const int q0 = qg * 128 + w * 16;
    const int t16 = qg * 8 + w;
    const u16* Qp = Qh + (size_t)bh * 131072;
    const u16* Kp = Kh + (size_t)bh * 131072;
    const u16* Vp = Vt + (size_t)bh * 131072;
    const u16* LGt = LGx + ((size_t)((b * 128 + t16) * 32) * 64 + lane) * 16;
    const f32x4 vzero = {0.f, 0.f, 0.f, 0.f};
    const s16x8 ones = {0x3F80, 0x3F80, 0x3F80, 0x3F80,
                        0x3F80, 0x3F80, 0x3F80, 0x3F80};  // bf16 1.0 x8

    // -------- precomputed LDS read bases (u16 units) --------
    const int s3 = l16 & 7, s2x = s3 & 3, s4x = s3 & 4;
    const int qsw = (quad ^ s2x) * 8;
    const int kb0 = l16 * 64 + qsw + s4x * 8;          // K, kc=0
    const int kb1 = l16 * 64 + qsw + (4 ^ s4x) * 8;    // K, kc=1
    const int vb0 = l16 * 128 + qsw + s4x * 8;         // V, kc32 even
    const int vb1 = l16 * 128 + qsw + (4 ^ s4x) * 8;   // V, kc32 odd
    const u16* KbL = &Ks[0][0];
    const u16* VbL = &Vs[0][0];

    // -------- staging: waves 0-3 K (32 key-rows each), 4-7 V (16 d-rows) ----
    const int w4 = w & 3;
    const bool isK = (w < 4);
    const int srK = lane >> 3, c8 = lane & 7;          // K: 8 rows x 8 chunks
    const int sr4 = lane >> 4, c16 = lane & 15;        // V: 4 rows x 16 chunks
    const u16* sg0 = isK
        ? (Kp + (size_t)(w4 * 32 + 0 + srK) * 64 + (c8 ^ srK) * 8)
        : (Vp + (size_t)(w4 * 16 + 0 + sr4) * 2048 + (c16 ^ ((0 + sr4) & 7)) * 8);
    const u16* sg1 = isK
        ? (Kp + (size_t)(w4 * 32 + 8 + srK) * 64 + (c8 ^ srK) * 8)
        : (Vp + (size_t)(w4 * 16 + 4 + sr4) * 2048 + (c16 ^ ((4 + sr4) & 7)) * 8);
    const u16* sg2 = isK
        ? (Kp + (size_t)(w4 * 32 + 16 + srK) * 64 + (c8 ^ srK) * 8)
        : (Vp + (size_t)(w4 * 16 + 8 + sr4) * 2048 + (c16 ^ ((8 + sr4) & 7)) * 8);
    const u16* sg3 = isK
        ? (Kp + (size_t)(w4 * 32 + 24 + srK) * 64 + (c8 ^ srK) * 8)
        : (Vp + (size_t)(w4 * 16 + 12 + sr4) * 2048 + (c16 ^ ((12 + sr4) & 7)) * 8);
    const size_t sAdv = isK ? 8192 : 128;   // u16 per 128-key tile
    u16* sd0 = isK ? &Ks[0][(w4 * 32 + 0) * 64]  : &Vs[0][(w4 * 16 + 0) * 128];
    u16* sd1 = isK ? &Ks[0][(w4 * 32 + 8) * 64]  : &Vs[0][(w4 * 16 + 4) * 128];
    u16* sd2 = isK ? &Ks[0][(w4 * 32 + 16) * 64] : &Vs[0][(w4 * 16 + 8) * 128];
    u16* sd3 = isK ? &Ks[0][(w4 * 32 + 24) * 64] : &Vs[0][(w4 * 16 + 12) * 128];

    s16x8 qf0 = *(const s16x8*)&Qp[(size_t)(q0 + l16) * 64 + quad * 8];
    s16x8 qf1 = *(const s16x8*)&Qp[(size_t)(q0 + l16) * 64 + 32 + quad * 8];
    f32x4 o[4], lacc = vzero;
#pragma unroll
    for (int dn = 0; dn < 4; ++dn) o[dn] = vzero;

    // prologue: stage tile 0 into buf 0; LG regs for tile 0
    gl2lds16(sg0, sd0); gl2lds16(sg1, sd1);
    gl2lds16(sg2, sd2); gl2lds16(sg3, sd3);
    sg0 += sAdv; sg1 += sAdv; sg2 += sAdv; sg3 += sAdv;
    uint4 lg0 = *(const uint4*)LGt;
    uint4 lg1 = *(const uint4*)(LGt + 8);
    uint4 lg2 = *(const uint4*)(LGt + 1024);
    uint4 lg3 = *(const uint4*)(LGt + 1032);
    const u16* lgP = LGt + 2048;

// QK quarter: 4 key-rows (kk block), LG words LA/LB -> Pw[PWB..PWB+3]
#define QKHALF(LA, LB, PWB, KOFF)                                              \
    {                                                                          \
        const u32 wdh[8] = {LA.x, LA.y, LA.z, LA.w, LB.x, LB.y, LB.z, LB.w};   \
        _Pragma("unroll")                                                      \
        for (int kk = 0; kk < 4; ++kk) {                                       \
            f32x4 ci;                                                          \
            ci[0] = bflo(wdh[kk * 2]);     ci[1] = bfhi(wdh[kk * 2]);          \
            ci[2] = bflo(wdh[kk * 2 + 1]); ci[3] = bfhi(wdh[kk * 2 + 1]);      \
            s16x8 ka = *(const s16x8*)(KbL + bo + kb0 + (KOFF + kk) * 1024);   \
            s16x8 kb = *(const s16x8*)(KbL + bo + kb1 + (KOFF + kk) * 1024);   \
            f32x4 s = __builtin_amdgcn_mfma_f32_16x16x32_bf16(ka, qf0, ci, 0, 0, 0); \
            s = __builtin_amdgcn_mfma_f32_16x16x32_bf16(kb, qf1, s, 0, 0, 0);  \
            float p0 = __builtin_amdgcn_exp2f(s[0]);                           \
            float p1 = __builtin_amdgcn_exp2f(s[1]);                           \
            float p2 = __builtin_amdgcn_exp2f(s[2]);                           \
            float p3 = __builtin_amdgcn_exp2f(s[3]);                           \
            Pw[PWB + kk][0] = pack_hi(p0, p1);                                 \
            Pw[PWB + kk][1] = pack_hi(p2, p3);                                 \
        }                                                                      \
    }

    for (int kt = 0; kt < 16; ++kt) {
        __syncthreads();  // tile[kt&1] staged, previous reads done
        const int bo = (kt & 1) * 8192;
        if (kt < 15) {    // prefetch tile kt+1 into the other buffer
            const int bn = 8192 - bo;
            gl2lds16(sg0, sd0 + bn); gl2lds16(sg1, sd1 + bn);
            gl2lds16(sg2, sd2 + bn); gl2lds16(sg3, sd3 + bn);
            sg0 += sAdv; sg1 += sAdv; sg2 += sAdv; sg3 += sAdv;
        }
        __builtin_amdgcn_s_setprio(1);
        // S^T = K.Q^T + LG, P = 2^S^T (bf16-truncated, packed)
        u32 Pw[8][2];
        QKHALF(lg0, lg1, 0, 0);
        QKHALF(lg2, lg3, 4, 4);
        if (kt < 15) {    // register-prefetch LG for tile kt+1
            lg0 = *(const uint4*)lgP;
            lg1 = *(const uint4*)(lgP + 8);
            lg2 = *(const uint4*)(lgP + 1024);
            lg3 = *(const uint4*)(lgP + 1032);
            lgP += 2048;
        }
        // PV + row-sum over 4 key-chunks of 32
#pragma unroll
        for (int kc = 0; kc < 4; ++kc) {
            union { u32 wrd[4]; s16x8 v; } pu;
#pragma unroll
            for (int i = 0; i < 2; ++i) {
                u32x2 r1 = __builtin_amdgcn_permlane32_swap(
                    Pw[2 * kc][i], Pw[2 * kc + 1][i], false, false);
                u32x2 r2 = __builtin_amdgcn_permlane16_swap(
                    r1[0], r1[1], false, false);
                pu.wrd[i]     = r2[0];
                pu.wrd[2 + i] = r2[1];
            }
            s16x8 pf = pu.v;
            lacc = __builtin_amdgcn_mfma_f32_16x16x32_bf16(pf, ones, lacc, 0, 0, 0);
            const int vbb = ((kc & 1) ? vb1 : vb0) + (kc >> 1) * 64 + bo;
#pragma unroll
            for (int dn = 0; dn < 4; ++dn) {
                s16x8 vf = *(const s16x8*)(VbL + vbb + dn * 2048);
                o[dn] = __builtin_amdgcn_mfma_f32_16x16x32_bf16(
                    pf, vf, o[dn], 0, 0, 0);
            }
        }
        __builtin_amdgcn_s_setprio(0);
    }
#undef QKHALF
    // lacc[reg] = sum_k P[q=quad*4+reg][k] — exactly the row this lane stores
#pragma unroll
    for (int reg = 0; reg < 4; ++reg) {
        float inv = __builtin_amdgcn_rcpf(lacc[reg]);
        int trow = b * 2048 + q0 + quad * 4 + reg;
#pragma unroll
        for (int dn = 0; dn < 4; ++dn)
            Ob[(size_t)trow * 512 + head * 64 + dn * 16 + l16] =
                f2bf(o[dn][reg] * inv);
    }
}

// ---------------------------------------------------------------------------
// Output projection: out = Ob @ Wo^T + bo, fp32 out.
// ---------------------------------------------------------------------------
__global__ __launch_bounds__(256) void out_kernel(
    const u16* __restrict__ Ob, const u16* __restrict__ cWo,
    const float* __restrict__ bo, float* __restrict__ out)
{
    __shared__ __align__(16) u16 As[2 * 4096];
    __shared__ __align__(16) u16 Bs[2 * 4096];
    const int m0 = blockIdx.y * 128, n0 = blockIdx.x * 128;
    f32x4 acc[4][4];
    gemm_core(Ob, cWo, m0, n0, As, Bs, acc);
    const int tid = threadIdx.x, lane = tid & 63, w = tid >> 6;
    const int wm = w >> 1, wn = w & 1, l16 = lane & 15, quad = lane >> 4;
#pragma unroll
    for (int nt = 0; nt < 4; ++nt) {
        int j = n0 + wn * 64 + nt * 16 + l16;
        float bj = bo[j];
#pragma unroll
        for (int mt = 0; mt < 4; ++mt) {
            int t = m0 + wm * 64 + mt * 16 + quad * 4;
#pragma unroll
            for (int reg = 0; reg < 4; ++reg)
                out[(size_t)(t + reg) * 512 + j] = acc[mt][nt][reg] + bj;
        }
    }
}

extern "C" void kernel_launch(void* const* d_in, const int* in_sizes, int n_in,
                              void* d_out, int out_size, void* d_ws, size_t ws_size,
                              hipStream_t stream)
{
    const float* Qin  = (const float*)d_in[0];
    const float* KVin = (const float*)d_in[1];
    const float* SC   = (const float*)d_in[2];
    const float* Wq   = (const float*)d_in[3];
    const float* bq   = (const float*)d_in[4];
    const float* Wk   = (const float*)d_in[5];
    const float* bk   = (const float*)d_in[6];
    const float* Wv   = (const float*)d_in[7];
    const float* bv   = (const float*)d_in[8];
    const float* gw   = (const float*)d_in[9];
    const float* gb   = (const float*)d_in[10];
    const float* Wo   = (const float*)d_in[11];
    const float* bo   = (const float*)d_in[12];
    float* out = (float*)d_out;

    // ws layout (u16 units): conv 9.4M | Qh/Kh/Vt/Ob 4.2M each | LGx 16.8M
    u16* conv = (u16*)d_ws;
    u16* cQin = conv;
    u16* cKV  = conv + 4194304;
    u16* cW   = conv + 8388608;        // Wq,Wk,Wv,Wo each 262,144
    u16* Qh   = conv + 9437184;
    u16* Kh   = Qh + 4194304;
    u16* Vt   = Kh + 4194304;
    u16* Ob   = Vt + 4194304;
    u16* LGx  = Ob + 4194304;          // 16,777,216 u16 = 32 MiB

    hipLaunchKernelGGL(prep_kernel, dim3(13312), dim3(256), 0, stream,
                       Qin, KVin, Wq, Wk, Wv, Wo, conv, SC, gw, gb, LGx);
    hipLaunchKernelGGL(proj_kernel, dim3(4, 64, 3), dim3(256), 0, stream,
                       cQin, cKV, cW, bq, bk, bv, Qh, Kh, Vt);
    hipLaunchKernelGGL(attn_kernel, dim3(16, 8, 4), dim3(512), 0, stream,
                       Qh, Kh, Vt, LGx, Ob);
    hipLaunchKernelGGL(out_kernel, dim3(4, 64), dim3(256), 0, stream,
                       Ob, cW + 786432, bo, out);
}

// Round 4
// 236.985 us; speedup vs baseline: 1.0264x; 1.0264x over previous
//
#include <hip/hip_runtime.h>

typedef unsigned short u16;
typedef unsigned int u32;
typedef __attribute__((ext_vector_type(4))) float f32x4;
typedef __attribute__((ext_vector_type(8))) short s16x8;
typedef __attribute__((ext_vector_type(4))) u16 u16x4;
typedef __attribute__((ext_vector_type(2))) u32 u32x2;

#define L2E 1.4426950408889634f
#define QSCALE 0.18033688011112042f /* (1/8) * log2(e) */

__device__ __forceinline__ float bf2f(u16 u) {
    union { u32 i; float f; } v; v.i = ((u32)u) << 16; return v.f;
}
__device__ __forceinline__ u16 f2bf(float f) {  // RNE
    union { float f; u32 i; } v; v.f = f;
    return (u16)((v.i + 0x7fffu + ((v.i >> 16) & 1u)) >> 16);
}
// pack hi16(a) | hi16(b)<<16  (bf16 truncation, 1-2 ops)
__device__ __forceinline__ u32 pack_hi(float a, float b) {
    union { float f; u32 i; } x, y; x.f = a; y.f = b;
    return (x.i >> 16) | (y.i & 0xFFFF0000u);
}
// bf16 stored in lo/hi half of a u32 -> f32 (1 VALU op each)
__device__ __forceinline__ float bflo(u32 w) {
    union { u32 i; float f; } v; v.i = w << 16; return v.f;
}
__device__ __forceinline__ float bfhi(u32 w) {
    union { u32 i; float f; } v; v.i = w & 0xFFFF0000u; return v.f;
}

// async global->LDS, 16B per lane; LDS dest = wave-uniform base + lane*16
__device__ __forceinline__ void gl2lds16(const u16* g, u16* l) {
    __builtin_amdgcn_global_load_lds(
        (const __attribute__((address_space(1))) void*)g,
        (__attribute__((address_space(3))) void*)l, 16, 0, 0);
}

// ---------------------------------------------------------------------------
// prep_kernel = conv (blocks 0..9215) + lg (blocks 9216..13311).
// conv: 6 fp32 tensors (Qin,KVin,Wq,Wk,Wv,Wo) -> bf16 flat region.
// lg:   LGx pre-swizzled gate, flat idx ((((b*128+t16)*32+kt)*64)+lane)*16
//       holds log2(sigmoid(gw*SC+gb)+1e-8) for q=t16*16+(lane&15),
//       k=kt*64+kk*16+(lane>>4)*4+reg.
// ---------------------------------------------------------------------------
__global__ __launch_bounds__(256) void prep_kernel(
    const float* __restrict__ s0, const float* __restrict__ s1,
    const float* __restrict__ s2, const float* __restrict__ s3,
    const float* __restrict__ s4, const float* __restrict__ s5,
    u16* __restrict__ dst,
    const float* __restrict__ SC, const float* __restrict__ gwp,
    const float* __restrict__ gbp, u16* __restrict__ LGx)
{
    if (blockIdx.x < 9216) {
        int e = (blockIdx.x * 256 + threadIdx.x) * 4;
        const float* src; int off;
        if      (e < 4194304) { src = s0; off = e; }
        else if (e < 8388608) { src = s1; off = e - 4194304; }
        else if (e < 8650752) { src = s2; off = e - 8388608; }
        else if (e < 8912896) { src = s3; off = e - 8650752; }
        else if (e < 9175040) { src = s4; off = e - 8912896; }
        else                  { src = s5; off = e - 9175040; }
        f32x4 f = *(const f32x4*)(src + off);
        u16x4 o;
#pragma unroll
        for (int j = 0; j < 4; ++j) o[j] = f2bf(f[j]);
        *(u16x4*)(dst + e) = o;
    } else {
        const int flat = (blockIdx.x - 9216) * 256 + threadIdx.x;
        const int lane = flat & 63;
        const int kt   = (flat >> 6) & 31;
        const int t16  = (flat >> 11) & 127;
        const int b    = flat >> 18;
        const int l16 = lane & 15, quad = lane >> 4;
        const float tA = -gwp[0] * L2E, tB = -gbp[0] * L2E;
        const float* row = SC + ((size_t)b * 2048 + t16 * 16 + l16) * 2048
                              + kt * 64 + quad * 4;
        __align__(16) u16 tmp[16];
#pragma unroll
        for (int kk = 0; kk < 4; ++kk) {
            f32x4 x = *(const f32x4*)(row + kk * 16);
#pragma unroll
            for (int reg = 0; reg < 4; ++reg) {
                float g = __builtin_amdgcn_rcpf(
                    1.0f + __builtin_amdgcn_exp2f(tA * x[reg] + tB)) + 1e-8f;
                tmp[kk * 4 + reg] = f2bf(__builtin_amdgcn_logf(g));  // log2
            }
        }
        u16* d = LGx + (size_t)flat * 16;
        *(uint4*)d       = *(uint4*)tmp;
        *(uint4*)(d + 8) = *(uint4*)(tmp + 8);
    }
}

// ---------------------------------------------------------------------------
// GEMM core, double-buffered: C[128x128] = A[128x512]*B^T, bf16.
// ---------------------------------------------------------------------------
__device__ __forceinline__ void gemm_core(
    const u16* __restrict__ A, const u16* __restrict__ Bw,
    int m0, int n0, u16* As, u16* Bs, f32x4 acc[4][4])
{
    const int tid = threadIdx.x;
    const int lane = tid & 63, w = tid >> 6;
    const int wm = w >> 1, wn = w & 1;
    const int l16 = lane & 15, quad = lane >> 4;
    const int srow = (lane >> 2), sch = (lane & 3) * 8;
    const f32x4 vzero = {0.f, 0.f, 0.f, 0.f};
#pragma unroll
    for (int i = 0; i < 4; ++i)
#pragma unroll
        for (int j = 0; j < 4; ++j) acc[i][j] = vzero;

    // prologue: stage kt=0 into buffer 0
#pragma unroll
    for (int j = 0; j < 2; ++j) {
        int row = w * 32 + j * 16 + srow;
        gl2lds16(&A[(size_t)(m0 + row) * 512 + sch], &As[w * 1024 + j * 512]);
        gl2lds16(&Bw[(size_t)(n0 + row) * 512 + sch], &Bs[w * 1024 + j * 512]);
    }
    for (int kt = 0; kt < 16; ++kt) {
        __syncthreads();  // buf[kt&1] ready (drains each wave's staging)
        const int cur = (kt & 1) * 4096;
        if (kt < 15) {
            const int nxt = ((kt + 1) & 1) * 4096;
#pragma unroll
            for (int j = 0; j < 2; ++j) {
                int row = w * 32 + j * 16 + srow;
                gl2lds16(&A[(size_t)(m0 + row) * 512 + (kt + 1) * 32 + sch],
                         &As[nxt + w * 1024 + j * 512]);
                gl2lds16(&Bw[(size_t)(n0 + row) * 512 + (kt + 1) * 32 + sch],
                         &Bs[nxt + w * 1024 + j * 512]);
            }
        }
        s16x8 af[4], bfr[4];
#pragma unroll
        for (int mt = 0; mt < 4; ++mt)
            af[mt] = *(const s16x8*)&As[cur + (wm * 64 + mt * 16 + l16) * 32 + quad * 8];
#pragma unroll
        for (int nt = 0; nt < 4; ++nt)
            bfr[nt] = *(const s16x8*)&Bs[cur + (wn * 64 + nt * 16 + l16) * 32 + quad * 8];
#pragma unroll
        for (int mt = 0; mt < 4; ++mt)
#pragma unroll
            for (int nt = 0; nt < 4; ++nt)
                acc[mt][nt] = __builtin_amdgcn_mfma_f32_16x16x32_bf16(
                    af[mt], bfr[nt], acc[mt][nt], 0, 0, 0);
    }
}

// ---------------------------------------------------------------------------
// QKV projection. job 0=Q (scaled, ->[B,H,N,64]), 1=K, 2=V (-> [B,H,64,N]).
// ---------------------------------------------------------------------------
__global__ __launch_bounds__(256) void proj_kernel(
    const u16* __restrict__ cQin, const u16* __restrict__ cKV,
    const u16* __restrict__ cW,
    const float* __restrict__ bq, const float* __restrict__ bk,
    const float* __restrict__ bv,
    u16* __restrict__ Qh, u16* __restrict__ Kh, u16* __restrict__ Vt)
{
    __shared__ __align__(16) u16 As[2 * 4096];
    __shared__ __align__(16) u16 Bs[2 * 4096];
    const int job = blockIdx.z;
    const u16* A = (job == 0) ? cQin : cKV;
    const u16* W = cW + (size_t)job * 262144;
    const float* bias = (job == 0) ? bq : (job == 1 ? bk : bv);
    const int m0 = blockIdx.y * 128, n0 = blockIdx.x * 128;
    f32x4 acc[4][4];
    gemm_core(A, W, m0, n0, As, Bs, acc);

    const int tid = threadIdx.x, lane = tid & 63, w = tid >> 6;
    const int wm = w >> 1, wn = w & 1, l16 = lane & 15, quad = lane >> 4;
#pragma unroll
    for (int nt = 0; nt < 4; ++nt) {
        int j = n0 + wn * 64 + nt * 16 + l16;
        float bj = bias[j];
        int h = j >> 6, d = j & 63;
#pragma unroll
        for (int mt = 0; mt < 4; ++mt) {
            int trow = m0 + wm * 64 + mt * 16 + quad * 4;
            int bb = trow >> 11, nn = trow & 2047;
            int bh = bb * 8 + h;
            if (job == 2) {
                u16x4 pv;
#pragma unroll
                for (int reg = 0; reg < 4; ++reg) pv[reg] = f2bf(acc[mt][nt][reg] + bj);
                *(u16x4*)&Vt[(size_t)(bh * 64 + d) * 2048 + nn] = pv;
            } else if (job == 0) {
#pragma unroll
                for (int reg = 0; reg < 4; ++reg)
                    Qh[(size_t)(bh * 2048 + nn + reg) * 64 + d] =
                        f2bf((acc[mt][nt][reg] + bj) * QSCALE);
            } else {
#pragma unroll
                for (int reg = 0; reg < 4; ++reg)
                    Kh[(size_t)(bh * 2048 + nn + reg) * 64 + d] =
                        f2bf(acc[mt][nt][reg] + bj);
            }
        }
    }
}

// ---------------------------------------------------------------------------
// Attention. Block = 512 thr = 8 waves = (1 head, 128 q-rows); wave = 16 q.
// Grid (16,8,4) = 512 blocks = 2/CU. KVBLK=128, 16 K-tiles, one barrier each.
// K tile: [128 key][64 d], 128-B rows, XOR-swizzled (conflict-free, as R2).
// V tile: TWO [64 d][64 key] sub-tiles (half = keys 0-63 / 64-127) — restores
// the 128-B-row stride that measured ZERO bank conflicts; the 256-B-row
// variant cost exactly +4 cyc per V ds_read_b128 (4.19M conflict cycles).
// LG folded into QK^T via MFMA C-init; P redistributed to the PV A-fragment
// layout with permlane32_swap+permlane16_swap (no LDS round trip).
// ---------------------------------------------------------------------------
__global__ __launch_bounds__(512, 4) void attn_kernel(
    const u16* __restrict__ Qh, const u16* __restrict__ Kh,
    const u16* __restrict__ Vt, const u16* __restrict__ LGx,
    u16* __restrict__ Ob)
{
    __shared__ __align__(16) u16 Ks[2][8192];  // [buf][key(128)][d(64)] swz
    __shared__ __align__(16) u16 Vs[2][8192];  // [buf][half(2)][d(64)][key(64)] swz
    const int tid = threadIdx.x;
    const int w = tid >> 6, lane = tid & 63;
    const int l16 = lane & 15, quad = lane >> 4;
    const int b = blockIdx.z, head = blockIdx.y, qg = blockIdx.x;
    const int bh = b * 8 + head;
    const int q0 = qg * 128 + w * 16;
    const int t16 = qg * 8 + w;
    const u16* Qp = Qh + (size_t)bh * 131072;
    const u16* Kp = Kh + (size_t)bh * 131072;
    const u16* Vp = Vt + (size_t)bh * 131072;
    const u16* LGt = LGx + ((size_t)((b * 128 + t16) * 32) * 64 + lane) * 16;
    const f32x4 vzero = {0.f, 0.f, 0.f, 0.f};
    const s16x8 ones = {0x3F80, 0x3F80, 0x3F80, 0x3F80,
                        0x3F80, 0x3F80, 0x3F80, 0x3F80};  // bf16 1.0 x8

    // -------- precomputed LDS read bases (u16 units) --------
    const int s3 = l16 & 7, s2x = s3 & 3, s4x = s3 & 4;
    const int qsw = (quad ^ s2x) * 8;
    const int kb0 = l16 * 64 + qsw + s4x * 8;          // K, kc even
    const int kb1 = l16 * 64 + qsw + (4 ^ s4x) * 8;    // K, kc odd
    const int vb0 = l16 * 64 + qsw + s4x * 8;          // V, kc even (in half)
    const int vb1 = l16 * 64 + qsw + (4 ^ s4x) * 8;    // V, kc odd  (in half)
    const u16* KbL = &Ks[0][0];
    const u16* VbL = &Vs[0][0];

    // -------- staging: waves 0-3 K (32 key-rows each), 4-7 V --------
    const int w4 = w & 3;
    const bool isK = (w < 4);
    const int sr = lane >> 3, c8 = lane & 7;           // 8 rows x 8 chunks
    const u16* sg0 = isK
        ? (Kp + (size_t)(w4 * 32 + 0 + sr) * 64 + (c8 ^ sr) * 8)
        : (Vp + (size_t)(w4 * 16 + 0 + sr) * 2048 + (c8 ^ sr) * 8);        // h0
    const u16* sg1 = isK
        ? (Kp + (size_t)(w4 * 32 + 8 + sr) * 64 + (c8 ^ sr) * 8)
        : (Vp + (size_t)(w4 * 16 + 8 + sr) * 2048 + (c8 ^ sr) * 8);        // h0
    const u16* sg2 = isK
        ? (Kp + (size_t)(w4 * 32 + 16 + sr) * 64 + (c8 ^ sr) * 8)
        : (Vp + (size_t)(w4 * 16 + 0 + sr) * 2048 + 64 + (c8 ^ sr) * 8);   // h1
    const u16* sg3 = isK
        ? (Kp + (size_t)(w4 * 32 + 24 + sr) * 64 + (c8 ^ sr) * 8)
        : (Vp + (size_t)(w4 * 16 + 8 + sr) * 2048 + 64 + (c8 ^ sr) * 8);   // h1
    const size_t sAdv = isK ? 8192 : 128;   // u16 per 128-key tile
    u16* sd0 = isK ? &Ks[0][(w4 * 32 + 0) * 64]  : &Vs[0][(w4 * 16 + 0) * 64];
    u16* sd1 = isK ? &Ks[0][(w4 * 32 + 8) * 64]  : &Vs[0][(w4 * 16 + 8) * 64];
    u16* sd2 = isK ? &Ks[0][(w4 * 32 + 16) * 64] : &Vs[0][4096 + (w4 * 16 + 0) * 64];
    u16* sd3 = isK ? &Ks[0][(w4 * 32 + 24) * 64] : &Vs[0][4096 + (w4 * 16 + 8) * 64];

    s16x8 qf0 = *(const s16x8*)&Qp[(size_t)(q0 + l16) * 64 + quad * 8];
    s16x8 qf1 = *(const s16x8*)&Qp[(size_t)(q0 + l16) * 64 + 32 + quad * 8];
    f32x4 o[4], lacc = vzero;
#pragma unroll
    for (int dn = 0; dn < 4; ++dn) o[dn] = vzero;

    // prologue: stage tile 0 into buf 0; LG regs for tile 0
    gl2lds16(sg0, sd0); gl2lds16(sg1, sd1);
    gl2lds16(sg2, sd2); gl2lds16(sg3, sd3);
    sg0 += sAdv; sg1 += sAdv; sg2 += sAdv; sg3 += sAdv;
    uint4 lg0 = *(const uint4*)LGt;
    uint4 lg1 = *(const uint4*)(LGt + 8);
    uint4 lg2 = *(const uint4*)(LGt + 1024);
    uint4 lg3 = *(const uint4*)(LGt + 1032);
    const u16* lgP = LGt + 2048;

// QK quarter: 4 key-rows (kk block), LG words LA/LB -> Pw[PWB..PWB+3]
#define QKHALF(LA, LB, PWB, KOFF)                                              \
    {                                                                          \
        const u32 wdh[8] = {LA.x, LA.y, LA.z, LA.w, LB.x, LB.y, LB.z, LB.w};   \
        _Pragma("unroll")                                                      \
        for (int kk = 0; kk < 4; ++kk) {                                       \
            f32x4 ci;                                                          \
            ci[0] = bflo(wdh[kk * 2]);     ci[1] = bfhi(wdh[kk * 2]);          \
            ci[2] = bflo(wdh[kk * 2 + 1]); ci[3] = bfhi(wdh[kk * 2 + 1]);      \
            s16x8 ka = *(const s16x8*)(KbL + bo + kb0 + (KOFF + kk) * 1024);   \
            s16x8 kb = *(const s16x8*)(KbL + bo + kb1 + (KOFF + kk) * 1024);   \
            f32x4 s = __builtin_amdgcn_mfma_f32_16x16x32_bf16(ka, qf0, ci, 0, 0, 0); \
            s = __builtin_amdgcn_mfma_f32_16x16x32_bf16(kb, qf1, s, 0, 0, 0);  \
            float p0 = __builtin_amdgcn_exp2f(s[0]);                           \
            float p1 = __builtin_amdgcn_exp2f(s[1]);                           \
            float p2 = __builtin_amdgcn_exp2f(s[2]);                           \
            float p3 = __builtin_amdgcn_exp2f(s[3]);                           \
            Pw[PWB + kk][0] = pack_hi(p0, p1);                                 \
            Pw[PWB + kk][1] = pack_hi(p2, p3);                                 \
        }                                                                      \
    }

    for (int kt = 0; kt < 16; ++kt) {
        __syncthreads();  // tile[kt&1] staged, previous reads done
        const int bo = (kt & 1) * 8192;
        if (kt < 15) {    // prefetch tile kt+1 into the other buffer
            const int bn = 8192 - bo;
            gl2lds16(sg0, sd0 + bn); gl2lds16(sg1, sd1 + bn);
            gl2lds16(sg2, sd2 + bn); gl2lds16(sg3, sd3 + bn);
            sg0 += sAdv; sg1 += sAdv; sg2 += sAdv; sg3 += sAdv;
        }
        __builtin_amdgcn_s_setprio(1);
        // S^T = K.Q^T + LG, P = 2^S^T (bf16-truncated, packed)
        u32 Pw[8][2];
        QKHALF(lg0, lg1, 0, 0);
        QKHALF(lg2, lg3, 4, 4);
        if (kt < 15) {    // register-prefetch LG for tile kt+1
            lg0 = *(const uint4*)lgP;
            lg1 = *(const uint4*)(lgP + 8);
            lg2 = *(const uint4*)(lgP + 1024);
            lg3 = *(const uint4*)(lgP + 1032);
            lgP += 2048;
        }
        // PV + row-sum over 4 key-chunks of 32
#pragma unroll
        for (int kc = 0; kc < 4; ++kc) {
            union { u32 wrd[4]; s16x8 v; } pu;
#pragma unroll
            for (int i = 0; i < 2; ++i) {
                u32x2 r1 = __builtin_amdgcn_permlane32_swap(
                    Pw[2 * kc][i], Pw[2 * kc + 1][i], false, false);
                u32x2 r2 = __builtin_amdgcn_permlane16_swap(
                    r1[0], r1[1], false, false);
                pu.wrd[i]     = r2[0];
                pu.wrd[2 + i] = r2[1];
            }
            s16x8 pf = pu.v;
            lacc = __builtin_amdgcn_mfma_f32_16x16x32_bf16(pf, ones, lacc, 0, 0, 0);
            const int vbb = ((kc & 1) ? vb1 : vb0) + (kc >> 1) * 4096 + bo;
#pragma unroll
            for (int dn = 0; dn < 4; ++dn) {
                s16x8 vf = *(const s16x8*)(VbL + vbb + dn * 1024);
                o[dn] = __builtin_amdgcn_mfma_f32_16x16x32_bf16(
                    pf, vf, o[dn], 0, 0, 0);
            }
        }
        __builtin_amdgcn_s_setprio(0);
    }
#undef QKHALF
    // lacc[reg] = sum_k P[q=quad*4+reg][k] — exactly the row this lane stores
#pragma unroll
    for (int reg = 0; reg < 4; ++reg) {
        float inv = __builtin_amdgcn_rcpf(lacc[reg]);
        int trow = b * 2048 + q0 + quad * 4 + reg;
#pragma unroll
        for (int dn = 0; dn < 4; ++dn)
            Ob[(size_t)trow * 512 + head * 64 + dn * 16 + l16] =
                f2bf(o[dn][reg] * inv);
    }
}

// ---------------------------------------------------------------------------
// Output projection: out = Ob @ Wo^T + bo, fp32 out.
// ---------------------------------------------------------------------------
__global__ __launch_bounds__(256) void out_kernel(
    const u16* __restrict__ Ob, const u16* __restrict__ cWo,
    const float* __restrict__ bo, float* __restrict__ out)
{
    __shared__ __align__(16) u16 As[2 * 4096];
    __shared__ __align__(16) u16 Bs[2 * 4096];
    const int m0 = blockIdx.y * 128, n0 = blockIdx.x * 128;
    f32x4 acc[4][4];
    gemm_core(Ob, cWo, m0, n0, As, Bs, acc);
    const int tid = threadIdx.x, lane = tid & 63, w = tid >> 6;
    const int wm = w >> 1, wn = w & 1, l16 = lane & 15, quad = lane >> 4;
#pragma unroll
    for (int nt = 0; nt < 4; ++nt) {
        int j = n0 + wn * 64 + nt * 16 + l16;
        float bj = bo[j];
#pragma unroll
        for (int mt = 0; mt < 4; ++mt) {
            int t = m0 + wm * 64 + mt * 16 + quad * 4;
#pragma unroll
            for (int reg = 0; reg < 4; ++reg)
                out[(size_t)(t + reg) * 512 + j] = acc[mt][nt][reg] + bj;
        }
    }
}

extern "C" void kernel_launch(void* const* d_in, const int* in_sizes, int n_in,
                              void* d_out, int out_size, void* d_ws, size_t ws_size,
                              hipStream_t stream)
{
    const float* Qin  = (const float*)d_in[0];
    const float* KVin = (const float*)d_in[1];
    const float* SC   = (const float*)d_in[2];
    const float* Wq   = (const float*)d_in[3];
    const float* bq   = (const float*)d_in[4];
    const float* Wk   = (const float*)d_in[5];
    const float* bk   = (const float*)d_in[6];
    const float* Wv   = (const float*)d_in[7];
    const float* bv   = (const float*)d_in[8];
    const float* gw   = (const float*)d_in[9];
    const float* gb   = (const float*)d_in[10];
    const float* Wo   = (const float*)d_in[11];
    const float* bo   = (const float*)d_in[12];
    float* out = (float*)d_out;

    // ws layout (u16 units): conv 9.4M | Qh/Kh/Vt/Ob 4.2M each | LGx 16.8M
    u16* conv = (u16*)d_ws;
    u16* cQin = conv;
    u16* cKV  = conv + 4194304;
    u16* cW   = conv + 8388608;        // Wq,Wk,Wv,Wo each 262,144
    u16* Qh   = conv + 9437184;
    u16* Kh   = Qh + 4194304;
    u16* Vt   = Kh + 4194304;
    u16* Ob   = Vt + 4194304;
    u16* LGx  = Ob + 4194304;          // 16,777,216 u16 = 32 MiB

    hipLaunchKernelGGL(prep_kernel, dim3(13312), dim3(256), 0, stream,
                       Qin, KVin, Wq, Wk, Wv, Wo, conv, SC, gw, gb, LGx);
    hipLaunchKernelGGL(proj_kernel, dim3(4, 64, 3), dim3(256), 0, stream,
                       cQin, cKV, cW, bq, bk, bv, Qh, Kh, Vt);
    hipLaunchKernelGGL(attn_kernel, dim3(16, 8, 4), dim3(512), 0, stream,
                       Qh, Kh, Vt, LGx, Ob);
    hipLaunchKernelGGL(out_kernel, dim3(4, 64), dim3(256), 0, stream,
                       Ob, cW + 786432, bo, out);
}